// Round 9
// baseline (336.722 us; speedup 1.0000x reference)
//
#include <hip/hip_runtime.h>
#include <stdint.h>

typedef int   int4v   __attribute__((ext_vector_type(4)));
typedef float float4v __attribute__((ext_vector_type(4)));

static constexpr int DIM = 4096;          // N = IN = OUT
static constexpr int BT  = 128;           // block tile (M and N)
static constexpr int BK  = 64;            // K-step bytes (1 MFMA k-step of K=64)
static constexpr int NKT = DIM / BK;      // 64

// ---------------- fused quantization kernel ----------------
// blocks [0, QB): activations (per-tensor scale); blocks [QB, 2*QB): weights (per-row scale)
static constexpr int QB = 2048;

__global__ __launch_bounds__(256) void quant_fused_kernel(
    const float* __restrict__ x, const float* __restrict__ wgt,
    const float* __restrict__ as_ptr, const int* __restrict__ azp_ptr,
    const float* __restrict__ ws, const int* __restrict__ wzp,
    int* __restrict__ a_out, int* __restrict__ b_out, int n4) {
  const bool isAct = (blockIdx.x < QB);
  const int  blk   = isAct ? blockIdx.x : blockIdx.x - QB;
  const float* src = isAct ? x : wgt;
  int* dst         = isAct ? a_out : b_out;
  const float sAct = as_ptr[0];
  const int   zpA  = azp_ptr[0];
  int idx    = blk * blockDim.x + threadIdx.x;
  int stride = QB * blockDim.x;
  for (int i = idx; i < n4; i += stride) {
    const float s = isAct ? sAct : ws[i >> 10];
    const int  zp = isAct ? zpA  : wzp[i >> 10];
    float4v v = reinterpret_cast<const float4v*>(src)[i];
    int packed = 0;
#pragma unroll
    for (int j = 0; j < 4; ++j) {
      int q = (int)rintf(v[j] / s) + zp;
      q = min(max(q, 0), 255);
      q -= zp;
      packed |= (q & 255) << (8 * j);
    }
    dst[i] = packed;
  }
}

// ---- int8 GEMM: 128^2 tile, 4 waves (wave tile 64x64), BK=64 -> 32 KiB dbuf ->
//      4-5 blocks/CU co-resident (cross-block slip = LDS<->MFMA overlap, m114)
//      with R8's 2:1 MFMA:ds_read economy. LDS-BW bound ~46 us/CU; R8 hit 62%
//      of it at 8 waves/CU; 16-20 waves/CU should reach 75-85%.
// Swizzle (64-B rows, 4 slots): LDS[row][slot^(row&3)] = global[row][slot];
// worst-case 2-way bank conflict = free (m136).

__global__ __launch_bounds__(256, 5) void gemm_i8_bk64(
    const signed char* __restrict__ A, const signed char* __restrict__ B,
    const float* __restrict__ s_act, const float* __restrict__ w_scale,
    const float* __restrict__ bias, float* __restrict__ C) {
  extern __shared__ signed char smem[];  // 2 x (A 8K + B 8K) = 32 KiB

  const int tid  = threadIdx.x;
  const int w    = tid >> 6;            // wave 0..3
  const int lane = tid & 63;
  const int wr = w >> 1, wc = w & 1;    // 2 x 2 wave grid; wave tile 64x64
  const int l15 = lane & 15, lhi = lane >> 4;
  const int swk = (l15 & 3) << 4;       // read-side XOR key ((row&3)<<4)

  const int srow = lane >> 2;                               // 0..15 row within chunk
  const int scol = ((lane & 3) ^ (srow & 3)) << 4;          // pre-swizzled global slot

  const int tileM = blockIdx.y * BT;
  const int tileN = blockIdx.x * BT;

  // chunk c covers tile rows 16c..16c+15 (16 rows x 64 B = 1 KiB); wave owns c=2w,2w+1
  auto stageA = [&](int i, int t) {
    signed char* dst = smem + (t & 1) * 16384;
    const int c = 2 * w + i;
    const size_t g = (size_t)(tileM + c * 16 + srow) * DIM + (size_t)t * BK + scol;
    __builtin_amdgcn_global_load_lds(
        (const __attribute__((address_space(1))) void*)(A + g),
        (__attribute__((address_space(3))) void*)(dst + c * 1024), 16, 0, 0);
  };
  auto stageB = [&](int i, int t) {
    signed char* dst = smem + (t & 1) * 16384 + 8192;
    const int c = 2 * w + i;
    const size_t g = (size_t)(tileN + c * 16 + srow) * DIM + (size_t)t * BK + scol;
    __builtin_amdgcn_global_load_lds(
        (const __attribute__((address_space(1))) void*)(B + g),
        (__attribute__((address_space(3))) void*)(dst + c * 1024), 16, 0, 0);
  };
  auto rdA = [&](const signed char* aL, int m) -> int4v {
    const int r = wr * 64 + m * 16 + l15;
    return *(const int4v*)(aL + r * BK + ((lhi * 16) ^ swk));
  };
  auto rdB = [&](const signed char* bL, int n) -> int4v {
    const int r = wc * 64 + n * 16 + l15;
    return *(const int4v*)(bL + r * BK + ((lhi * 16) ^ swk));
  };

  int4v acc[4][4] = {};   // [m][n]
  int4v af[4], bf[4];

  // ---- prologue: stage tile 0 -> buf0
  stageA(0, 0); stageA(1, 0); stageB(0, 0); stageB(1, 0);
  asm volatile("s_waitcnt vmcnt(0)" ::: "memory");
  __builtin_amdgcn_s_barrier();

  for (int kt = 0; kt < NKT; ++kt) {
    const signed char* aC = smem + (kt & 1) * 16384;
    const signed char* bC = aC + 8192;

    // stage kt+1 into the other buffer (in flight during this tile's compute)
    if (kt + 1 < NKT) {
      stageA(0, kt + 1); stageA(1, kt + 1);
      stageB(0, kt + 1); stageB(1, kt + 1);
    }

    // read this tile's fragments (compiler inserts fine-grained lgkmcnt)
#pragma unroll
    for (int m = 0; m < 4; ++m) af[m] = rdA(aC, m);
#pragma unroll
    for (int n = 0; n < 4; ++n) bf[n] = rdB(bC, n);

    __builtin_amdgcn_s_setprio(1);
#pragma unroll
    for (int m = 0; m < 4; ++m)
#pragma unroll
      for (int n = 0; n < 4; ++n)
        acc[m][n] = __builtin_amdgcn_mfma_i32_16x16x64_i8(
            af[m], bf[n], acc[m][n], 0, 0, 0);
    __builtin_amdgcn_s_setprio(0);

    asm volatile("s_waitcnt vmcnt(0)" ::: "memory");  // kt+1 landed
    __builtin_amdgcn_s_barrier();                     // all reads consumed; buffers swap
  }

  // ---- epilogue: C/D layout col=lane&15, row=(lane>>4)*4+j
  const float sa = s_act[0];
#pragma unroll
  for (int n = 0; n < 4; ++n) {
    const int col = tileN + wc * 64 + n * 16 + l15;
    const float sc = sa * w_scale[col];
    const float bs = bias[col];
#pragma unroll
    for (int m = 0; m < 4; ++m) {
      const int rbase = tileM + wr * 64 + m * 16 + lhi * 4;
#pragma unroll
      for (int j = 0; j < 4; ++j)
        C[(size_t)(rbase + j) * DIM + col] = (float)acc[m][n][j] * sc + bs;
    }
  }
}

// ---------------- launch ----------------
extern "C" void kernel_launch(void* const* d_in, const int* in_sizes, int n_in,
                              void* d_out, int out_size, void* d_ws, size_t ws_size,
                              hipStream_t stream) {
  const float* x    = (const float*)d_in[0];
  const float* w    = (const float*)d_in[1];
  const float* bias = (const float*)d_in[2];
  const float* a_s  = (const float*)d_in[3];
  const int*   a_zp = (const int*)d_in[4];
  const float* w_s  = (const float*)d_in[5];
  const int*   w_zp = (const int*)d_in[6];
  float* out = (float*)d_out;

  signed char* a8 = (signed char*)d_ws;
  signed char* b8 = a8 + (size_t)DIM * DIM;

  const int n4 = DIM * DIM / 4;
  quant_fused_kernel<<<2 * QB, 256, 0, stream>>>(x, w, a_s, a_zp, w_s, w_zp,
                                                 (int*)a8, (int*)b8, n4);

  (void)hipFuncSetAttribute((const void*)gemm_i8_bk64,
                            hipFuncAttributeMaxDynamicSharedMemorySize, 32768);
  dim3 grid(DIM / BT, DIM / BT);  // 32 x 32 = 1024 blocks -> 4-5 resident/CU
  gemm_i8_bk64<<<grid, 256, 32768, stream>>>(a8, b8, a_s, w_s, bias, out);
}

// Round 10
// 114.627 us; speedup vs baseline: 2.9376x; 2.9376x over previous
//
#include <hip/hip_runtime.h>
#include <stdint.h>

typedef int   int4v   __attribute__((ext_vector_type(4)));
typedef float float4v __attribute__((ext_vector_type(4)));

static constexpr int DIM = 4096;          // N = IN = OUT
static constexpr int BT  = 128;           // block tile (M and N)
static constexpr int BK  = 128;           // K-step bytes (2 MFMA k-steps of K=64)
static constexpr int NKT = DIM / BK;      // 32

// ---------------- quantization: activations (row-major int8 out) ----------------
__global__ __launch_bounds__(256) void quant_act_kernel(
    const float* __restrict__ x, const float* __restrict__ s_ptr,
    const int* __restrict__ zp_ptr, int* __restrict__ out, int n4) {
  const float s  = s_ptr[0];
  const int   zp = zp_ptr[0];
  int idx    = blockIdx.x * blockDim.x + threadIdx.x;
  int stride = gridDim.x * blockDim.x;
  for (int i = idx; i < n4; i += stride) {
    float4v v = reinterpret_cast<const float4v*>(x)[i];
    int packed = 0;
#pragma unroll
    for (int j = 0; j < 4; ++j) {
      int q = (int)rintf(v[j] / s) + zp;
      q = min(max(q, 0), 255);
      q -= zp;
      packed |= (q & 255) << (8 * j);
    }
    out[i] = packed;
  }
}

// ---------------- quantization: weights -> MFMA-fragment-linear layout ----------------
// Fragment f = (row16 * NKT + kt) * 2 + kk  (row16 = row/16), 1024 B each.
// Bp[f][lane*16 .. +16] = int8(W[row16*16 + (lane&15)][kt*128 + kk*64 + (lane>>4)*16 ..])
// so a GEMM wave's B-operand load is one contiguous, coalesced 1-KB global_load_dwordx4.
__global__ __launch_bounds__(256) void quant_wgt_frag(
    const float* __restrict__ w, const float* __restrict__ ws,
    const int* __restrict__ wzp, int4v* __restrict__ bp) {
  const int t    = threadIdx.x;
  const int wv   = t >> 6, lane = t & 63;
  const int l15  = lane & 15, lhi = lane >> 4;
  const int NFRAG = (DIM / 16) * NKT * 2;          // 16384
  for (int f = blockIdx.x * 4 + wv; f < NFRAG; f += gridDim.x * 4) {
    const int row16 = f >> 6;                      // f / (NKT*2)
    const int rem   = f & 63;
    const int kt    = rem >> 1, kk = rem & 1;
    const int row   = row16 * 16 + l15;
    const int col   = kt * 128 + kk * 64 + lhi * 16;  // float (==byte) index
    const float s = ws[row];
    const int  zp = wzp[row];
    int4v q;
#pragma unroll
    for (int v4 = 0; v4 < 4; ++v4) {
      float4v xv = *reinterpret_cast<const float4v*>(w + (size_t)row * DIM + col + v4 * 4);
      int packed = 0;
#pragma unroll
      for (int j = 0; j < 4; ++j) {
        int qq = (int)rintf(xv[j] / s) + zp;
        qq = min(max(qq, 0), 255);
        qq -= zp;
        packed |= (qq & 255) << (8 * j);
      }
      q[v4] = packed;
    }
    bp[(size_t)f * 64 + lane] = q;
  }
}

// ---- int8 GEMM: 128^2 tile, 4 waves (64x64 wave tile), A via 32 KiB dbuf LDS,
//      B direct global->VGPR from fragment-linear Bp (no LDS for B) ->
//      3 blocks/CU co-resident. Per K-tile/block: MFMA 653 cy, A-LDS ~375 cy,
//      B-from-L2 ~570 cy -> MFMA-bound under 3-block overlap (m114 slip).

__global__ __launch_bounds__(256, 3) void gemm_i8_bdir(
    const signed char* __restrict__ A, const int4v* __restrict__ Bp,
    const float* __restrict__ s_act, const float* __restrict__ w_scale,
    const float* __restrict__ bias, float* __restrict__ C) {
  extern __shared__ signed char smem[];  // 2 x (A 16K) = 32 KiB

  const int tid  = threadIdx.x;
  const int w    = tid >> 6;            // wave 0..3
  const int lane = tid & 63;
  const int wr = w >> 1, wc = w & 1;    // 2 x 2 wave grid; wave tile 64x64
  const int l15 = lane & 15, lhi = lane >> 4;
  const int swk = (l15 & 7) << 4;       // read-side XOR swizzle key ((row&7)<<4) [R7/R8-verified]

  const int srow = lane >> 3;                           // staging row within 8-row chunk
  const int scol = ((lane & 7) ^ (lane >> 3)) << 4;     // pre-swizzled global col

  const int tileM = blockIdx.y * BT;
  const int tileN = blockIdx.x * BT;
  const int rb16  = (tileN >> 4) + wc * 4;              // base row16 of this wave's B panel

  // A staging: chunk c covers tile rows 8c..8c+7 (1 KiB); wave w owns chunks 4w..4w+3
  auto stageA = [&](int i, int t) {
    signed char* dst = smem + (t & 1) * 16384;
    const int c = 4 * w + i;
    const size_t g = (size_t)(tileM + c * 8 + srow) * DIM + (size_t)t * BK + scol;
    __builtin_amdgcn_global_load_lds(
        (const __attribute__((address_space(1))) void*)(A + g),
        (__attribute__((address_space(3))) void*)(dst + c * 1024), 16, 0, 0);
  };
  auto rdA = [&](const signed char* aL, int m, int kk) -> int4v {
    const int r = wr * 64 + m * 16 + l15;
    return *(const int4v*)(aL + r * BK + ((kk * 64 + lhi * 16) ^ swk));
  };
  auto ldB = [&](int n, int kt, int kk) -> int4v {
    const size_t f = ((size_t)(rb16 + n) * NKT + kt) * 2 + kk;
    return Bp[f * 64 + lane];
  };

  int4v acc[4][4] = {};   // [m][n]
  int4v af[4][2];         // [m][kk]
  int4v bf[4][2];         // [n][kk]

  // ---- prologue: stage A tile 0 -> buf0
#pragma unroll
  for (int i = 0; i < 4; ++i) stageA(i, 0);
  asm volatile("s_waitcnt vmcnt(0)" ::: "memory");
  __builtin_amdgcn_s_barrier();

  for (int kt = 0; kt < NKT; ++kt) {
    const signed char* aC = smem + (kt & 1) * 16384;

    // B fragments for this tile: coalesced 1-KB loads straight to VGPRs
#pragma unroll
    for (int n = 0; n < 4; ++n) { bf[n][0] = ldB(n, kt, 0); bf[n][1] = ldB(n, kt, 1); }

    // stage A(kt+1) into the other buffer (in flight during this tile's compute)
    if (kt + 1 < NKT) {
#pragma unroll
      for (int i = 0; i < 4; ++i) stageA(i, kt + 1);
    }

    // A fragments from LDS (compiler inserts fine-grained lgkmcnt)
#pragma unroll
    for (int m = 0; m < 4; ++m) { af[m][0] = rdA(aC, m, 0); af[m][1] = rdA(aC, m, 1); }

    __builtin_amdgcn_s_setprio(1);
#pragma unroll
    for (int kk = 0; kk < 2; ++kk)
#pragma unroll
      for (int m = 0; m < 4; ++m)
#pragma unroll
        for (int n = 0; n < 4; ++n)
          acc[m][n] = __builtin_amdgcn_mfma_i32_16x16x64_i8(
              af[m][kk], bf[n][kk], acc[m][n], 0, 0, 0);
    __builtin_amdgcn_s_setprio(0);

    // B loads were consumed by MFMA (already retired); this waits only A stages.
    asm volatile("s_waitcnt vmcnt(0)" ::: "memory");
    __builtin_amdgcn_s_barrier();
  }

  // ---- epilogue: C/D layout col=lane&15, row=(lane>>4)*4+j
  const float sa = s_act[0];
#pragma unroll
  for (int n = 0; n < 4; ++n) {
    const int col = tileN + wc * 64 + n * 16 + l15;
    const float sc = sa * w_scale[col];
    const float bs = bias[col];
#pragma unroll
    for (int m = 0; m < 4; ++m) {
      const int rbase = tileM + wr * 64 + m * 16 + lhi * 4;
#pragma unroll
      for (int j = 0; j < 4; ++j)
        C[(size_t)(rbase + j) * DIM + col] = (float)acc[m][n][j] * sc + bs;
    }
  }
}

// ---------------- launch ----------------
extern "C" void kernel_launch(void* const* d_in, const int* in_sizes, int n_in,
                              void* d_out, int out_size, void* d_ws, size_t ws_size,
                              hipStream_t stream) {
  const float* x    = (const float*)d_in[0];
  const float* w    = (const float*)d_in[1];
  const float* bias = (const float*)d_in[2];
  const float* a_s  = (const float*)d_in[3];
  const int*   a_zp = (const int*)d_in[4];
  const float* w_s  = (const float*)d_in[5];
  const int*   w_zp = (const int*)d_in[6];
  float* out = (float*)d_out;

  signed char* a8 = (signed char*)d_ws;                    // 16 MB row-major activations
  int4v*       bp = (int4v*)(a8 + (size_t)DIM * DIM);      // 16 MB fragment-linear weights

  const int n4 = DIM * DIM / 4;
  quant_act_kernel<<<2048, 256, 0, stream>>>(x, a_s, a_zp, (int*)a8, n4);
  quant_wgt_frag<<<2048, 256, 0, stream>>>(w, w_s, w_zp, bp);

  (void)hipFuncSetAttribute((const void*)gemm_i8_bdir,
                            hipFuncAttributeMaxDynamicSharedMemorySize, 32768);
  dim3 grid(DIM / BT, DIM / BT);  // 32 x 32 = 1024 blocks -> 3 resident/CU
  gemm_i8_bdir<<<grid, 256, 32768, stream>>>(a8, bp, a_s, w_s, bias, out);
}